// Round 13
// baseline (273.544 us; speedup 1.0000x reference)
//
#include <hip/hip_runtime.h>
#include <math.h>

#define T_STEPS 256
#define Fdim 32
#define Udim 64
#define G4 256            // 4*U
#define OUT_STEPS 24
#define ROWS 16           // batch rows per block (= MFMA N)
#define NBLK 256          // 4096 / 16
#define NTHR 512          // 8 waves, 2 waves/SIMD: measured-best partition
#define HBS 72            // row stride in shorts (144 B, 36 dwords: measured-best layout)
#define CHUNK 16
#define NCHUNK 16         // 16 * 16 = 256 steps
#define LOG2E 1.4426950408889634f

typedef __attribute__((ext_vector_type(8))) short short8;   // 8 bf16 = 4 VGPR
typedef __attribute__((ext_vector_type(4))) float f32x4;

__device__ __forceinline__ short f2bf(float f) {
    union { float f; unsigned u; } v; v.f = f;
    unsigned r = v.u + 0x7FFFu + ((v.u >> 16) & 1u);   // RNE
    return (short)(r >> 16);
}
__device__ __forceinline__ float bf2f(short s) {
    union { unsigned u; float f; } v; v.u = ((unsigned)(unsigned short)s) << 16;
    return v.f;
}
__device__ __forceinline__ float frcp(float v) { return __builtin_amdgcn_rcpf(v); }
__device__ __forceinline__ float fexp2(float v) { return __builtin_amdgcn_exp2f(v); }

// packed f32x2 -> bf16x2 (RNE), 1 instruction
__device__ __forceinline__ unsigned pkbf(float lo, float hi) {
    unsigned r;
    asm("v_cvt_pk_bf16_f32 %0, %1, %2" : "=v"(r) : "v"(lo), "v"(hi));
    return r;
}

// LSTM cell with combined reciprocals (3 rcp; v17's 2-rcp repack LENGTHENED the
// chain and lost ILP between the two cells -- keep two independent scalar chains).
// Gates pre-scaled: i,f,o by log2e; g by 2*log2e.
__device__ __forceinline__ float cell_h(const f32x4 a, float& cst) {
    float A  = fexp2(-a[0]);
    float Bv = fexp2(a[2]);
    float rf = frcp(1.0f + fexp2(-a[1]));
    float ig = (Bv - 1.0f) * frcp((1.0f + A) * (1.0f + Bv));
    cst = fmaf(cst, rf, ig);
    float C  = fexp2(-a[3]);
    float D  = fexp2(2.0f * LOG2E * cst);
    return (D - 1.0f) * frcp((1.0f + C) * (1.0f + D));
}

// raw barrier: drains LDS (lgkmcnt) only -- NOT vmcnt -- so prefetched global
// loads stay in flight across the per-step barriers.
#define BAR() asm volatile("s_waitcnt lgkmcnt(0)\n\ts_barrier" ::: "memory")

#define MFMA __builtin_amdgcn_mfma_f32_16x16x32_bf16

// Phase-staggered wave priorities: odd waves get issue priority through the
// LDS-read + MFMA phase, even waves through the cell/trans phase. The per-step
// barrier re-syncs both waves/SIMD into the SAME phase each interval (measured:
// components add, ~zero cross-overlap); this manufactures a half-interval skew
// so one wave's LDS/MFMA overlaps the other's transcendentals.
#define PRIO_MFMA_PHASE()  do { if (w & 1) __builtin_amdgcn_s_setprio(1); } while (0)
#define PRIO_CELL_PHASE()  do { if (w & 1) __builtin_amdgcn_s_setprio(0); \
                                else       __builtin_amdgcn_s_setprio(1); } while (0)
#define PRIO_RESET()       do { if (!(w & 1)) __builtin_amdgcn_s_setprio(0); } while (0)

// z^T = Wt[256 gate-rows x 96] @ hx^T[96 x 16 rows], tile t covers gate-rows t*16..t*16+15.
// Wave w (0..7) owns tiles 2w, 2w+1 -> lane (q,m) owns cells (units w*8+q*2, w*8+q*2+1; row m)
// A-frag: lane l holds A[m=l&15][k=(l>>4)*8+j] (static pre-scaled weights in VGPRs)
// B-frag: lane l holds B[k=(l>>4)*8+j][n=l&15] (hb reads; x frags register-resident per chunk)
// C/D:    lane l holds D[row=q*4+reg][col=m]   (4 gates of one cell per lane)
// Decode folded: Ueff = U2 + Wd@W2, beff = b2 + bd@W2 (cooperative fp32 fold);
// fp32 pred via hi/lo-split Wd MFMAs on waves 0,1, off the sync path.
__global__ __launch_bounds__(NTHR, 2)
void lstm_v19(const float* __restrict__ x,
              const float* __restrict__ W1, const float* __restrict__ U1, const float* __restrict__ b1,
              const float* __restrict__ W2, const float* __restrict__ U2, const float* __restrict__ b2,
              const float* __restrict__ Wd, const float* __restrict__ bd,
              float* __restrict__ out)
{
    __shared__ __align__(16) short hb[2][ROWS][HBS];     // bf16 h, ping-pong
    __shared__ __align__(16) short xs[CHUNK][ROWS][HBS]; // bf16 x chunk
    __shared__ __align__(16) float WdLf[Udim][Fdim];     // Wd staged fp32 (fold input)
    __shared__ __align__(16) unsigned short UeffB[Udim][G4]; // folded U2+Wd@W2, pre-scaled bf16
    __shared__ float beffL[G4];                          // folded b2+bd@W2, fp32 unscaled

    const int tid = threadIdx.x;
    const int l   = tid & 63;
    const int w   = tid >> 6;         // wave 0..7
    const int q   = l >> 4;
    const int m   = l & 15;
    const int brow = blockIdx.x * ROWS;

    // ---- prefetch chunk 0 of x into registers (hide HBM latency under staging) ----
    const int f4  = tid & 7;          // float4 column 0..7
    const int tt  = (tid >> 3) & 15;  // step within chunk
    const int xr0 = tid >> 7;         // base row 0..3; rows xr0+4i
    float4 pf[4];
#pragma unroll
    for (int i = 0; i < 4; ++i)
        pf[i] = *(const float4*)&x[((size_t)(brow + xr0 + 4 * i) * T_STEPS + tt) * Fdim + f4 * 4];

    // ---- stage LSTM1 weights as register-resident A-fragments (pre-scaled) ----
    short8 wa1[2][3];
    f32x4 bs1[2];
#pragma unroll
    for (int nt = 0; nt < 2; ++nt) {
        const int unit_a = w * 8 + (m >> 2) * 2 + nt;  // A-row m -> (unit, gate)
        const int gate_a = m & 3;
        const int col = gate_a * 64 + unit_a;          // column in original [4U] layout
        const float sA = (gate_a == 2) ? 2.0f * LOG2E : LOG2E;
#pragma unroll
        for (int kt = 0; kt < 3; ++kt) {
            short8 fa;
#pragma unroll
            for (int j = 0; j < 8; ++j) {
                const int k = kt * 32 + q * 8 + j;
                fa[j] = f2bf(((k < Udim) ? U1[k * G4 + col] : W1[(k - Udim) * G4 + col]) * sA);
            }
            wa1[nt][kt] = fa;
        }
        const int unit_d = w * 8 + q * 2 + nt;
#pragma unroll
        for (int g = 0; g < 4; ++g) {
            const float sD = (g == 2) ? 2.0f * LOG2E : LOG2E;
            bs1[nt][g] = b1[g * 64 + unit_d] * sD;
        }
    }

    // ---- dense-output weights as hi/lo bf16 A-fragments (tile = wave 0 or 1) ----
    short8 wdh[2], wdlo[2];
    f32x4 bdC;
    {
        const int wsel = (w < 2) ? w : 0;              // avoid OOB for unused waves
#pragma unroll
        for (int kt = 0; kt < 2; ++kt) {
            short8 fh, fl;
#pragma unroll
            for (int j = 0; j < 8; ++j) {
                const float v = Wd[(kt * 32 + q * 8 + j) * Fdim + 16 * wsel + m];
                const short hi = f2bf(v);
                fh[j] = hi;
                fl[j] = f2bf(v - bf2f(hi));
            }
            wdh[kt] = fh;
            wdlo[kt] = fl;
        }
#pragma unroll
        for (int g = 0; g < 4; ++g) bdC[g] = bd[16 * wsel + q * 4 + g];
    }

    const int hw = w * 8 + q * 2;     // packed h write index (even)

    // ---- cooperative fold staging (each Ueff element computed once; v12 lesson) ----
    for (int idx = tid; idx < 2 * ROWS * HBS; idx += NTHR) ((short*)hb)[idx] = 0;
    for (int idx = tid; idx < Udim * Fdim; idx += NTHR) ((float*)WdLf)[idx] = Wd[idx];
    BAR();                            // WdLf (and hb zero) visible
    {
        const int colf = tid & 255;   // output column (coalesced)
        const int kh   = tid >> 8;    // k half: rows kh*32 .. kh*32+31
        float w2col[Fdim];            // W2[:, colf] -- coalesced loads, registers
#pragma unroll
        for (int f = 0; f < Fdim; ++f) w2col[f] = W2[f * G4 + colf];
        const float sAf = ((colf >> 6) == 2) ? 2.0f * LOG2E : LOG2E;
#pragma unroll
        for (int e = 0; e < 32; ++e) {
            const int k = kh * 32 + e;
            float v = U2[(size_t)k * G4 + colf];       // coalesced
#pragma unroll
            for (int f = 0; f < Fdim; ++f)
                v = fmaf(WdLf[k][f], w2col[f], v);     // LDS broadcast (wave-uniform)
            UeffB[k][colf] = (unsigned short)f2bf(v * sAf);
        }
        if (tid < G4) {               // beff = b2 + bd @ W2 (reuses w2col)
            float v = b2[colf];
#pragma unroll
            for (int f = 0; f < Fdim; ++f) v = fmaf(bd[f], w2col[f], v);
            beffL[colf] = v;
        }
    }
    BAR();                            // UeffB, beffL visible

    // ---- extract decode A-fragments from folded LDS ----
    short8 wa2[2][2];
    f32x4 bs2[2];
#pragma unroll
    for (int nt = 0; nt < 2; ++nt) {
        const int unit_a = w * 8 + (m >> 2) * 2 + nt;
        const int col = (m & 3) * 64 + unit_a;
#pragma unroll
        for (int kt = 0; kt < 2; ++kt) {
            short8 fb;
#pragma unroll
            for (int j = 0; j < 8; ++j)
                fb[j] = (short)UeffB[kt * 32 + q * 8 + j][col];
            wa2[nt][kt] = fb;
        }
        const int unit_d = w * 8 + q * 2 + nt;
#pragma unroll
        for (int g = 0; g < 4; ++g) {
            const float sD = (g == 2) ? 2.0f * LOG2E : LOG2E;
            bs2[nt][g] = beffL[g * 64 + unit_d] * sD;
        }
    }

    float cst[2] = {0.f, 0.f};

    // ================= warmup: 16 chunks x 16 steps, 1 raw barrier/step =================
    for (int c = 0; c < NCHUNK; ++c) {
        // convert prefetched chunk to bf16 and stage
#pragma unroll
        for (int i = 0; i < 4; ++i) {
            uint2 pk;
            pk.x = pkbf(pf[i].x, pf[i].y);
            pk.y = pkbf(pf[i].z, pf[i].w);
            *(uint2*)&xs[tt][xr0 + 4 * i][f4 * 4] = pk;
        }
        // issue next chunk's loads; they stay in flight across all 16 step barriers
        if (c + 1 < NCHUNK) {
#pragma unroll
            for (int i = 0; i < 4; ++i)
                pf[i] = *(const float4*)&x[((size_t)(brow + xr0 + 4 * i) * T_STEPS + ((c + 1) * CHUNK + tt)) * Fdim + f4 * 4];
        }
        BAR();                        // xs visible

        // burst-read the chunk's x B-frags into registers (off the step critical path)
        short8 xf[CHUNK];
#pragma unroll
        for (int t = 0; t < CHUNK; ++t)
            xf[t] = *(const short8*)&xs[t][m][q * 8];

#pragma unroll
        for (int t2 = 0; t2 < CHUNK; ++t2) {
            const int p = t2 & 1;     // c*16 even -> parity continues across chunks

            PRIO_MFMA_PHASE();        // odd waves sprint through read+MFMA

            const short8 b0  = *(const short8*)&hb[p][m][q * 8];
            const short8 b1v = *(const short8*)&hb[p][m][32 + q * 8];

            // x-MFMAs first: operands already in regs -> issue at barrier release,
            // covering the h-frag ds_read latency
            f32x4 a0 = MFMA(wa1[0][2], xf[t2], bs1[0], 0, 0, 0);
            f32x4 a1 = MFMA(wa1[1][2], xf[t2], bs1[1], 0, 0, 0);
            a0 = MFMA(wa1[0][0], b0, a0, 0, 0, 0);
            a1 = MFMA(wa1[1][0], b0, a1, 0, 0, 0);
            a0 = MFMA(wa1[0][1], b1v, a0, 0, 0, 0);
            a1 = MFMA(wa1[1][1], b1v, a1, 0, 0, 0);

            PRIO_CELL_PHASE();        // even waves get the trans/VALU phase

            const float h0 = cell_h(a0, cst[0]);
            const float h1 = cell_h(a1, cst[1]);
            *(unsigned*)&hb[1 - p][m][hw] = pkbf(h0, h1);

            PRIO_RESET();             // equal priority at the barrier
            BAR();                    // doubles as pre-stage barrier for next chunk
        }
    }

    // ================= decode: 23 folded LSTM steps, 1 barrier/step =================
    // h(final warmup) in hb[0]. Iteration s: read h(s-1), compute h(s) via
    // Ueff/beff, and emit pred(s-1) = h(s-1)@Wd + bd (waves 0,1; off sync path).
    int dp = 0;
    for (int s = 1; s < OUT_STEPS; ++s) {
        PRIO_MFMA_PHASE();

        const short8 b0p = *(const short8*)&hb[dp][m][q * 8];
        const short8 b1p = *(const short8*)&hb[dp][m][32 + q * 8];

        f32x4 a0 = MFMA(wa2[0][0], b0p, bs2[0], 0, 0, 0);
        f32x4 a1 = MFMA(wa2[1][0], b0p, bs2[1], 0, 0, 0);
        a0 = MFMA(wa2[0][1], b1p, a0, 0, 0, 0);
        a1 = MFMA(wa2[1][1], b1p, a1, 0, 0, 0);

        PRIO_CELL_PHASE();

        const float h0 = cell_h(a0, cst[0]);
        const float h1 = cell_h(a1, cst[1]);
        *(unsigned*)&hb[1 - dp][m][hw] = pkbf(h0, h1);

        if (w < 2) {                  // fp32 pred output
            f32x4 pz = MFMA(wdh[0], b0p, bdC, 0, 0, 0);
            pz = MFMA(wdh[1], b1p, pz, 0, 0, 0);
            pz = MFMA(wdlo[0], b0p, pz, 0, 0, 0);
            pz = MFMA(wdlo[1], b1p, pz, 0, 0, 0);
            *(f32x4*)&out[(size_t)(brow + m) * (OUT_STEPS * Fdim) + (s - 1) * Fdim + 16 * w + q * 4] = pz;
        }
        PRIO_RESET();
        BAR();
        dp = 1 - dp;
    }
    // final pred(23) from h(23) in hb[dp]
    if (w < 2) {
        const short8 b0p = *(const short8*)&hb[dp][m][q * 8];
        const short8 b1p = *(const short8*)&hb[dp][m][32 + q * 8];
        f32x4 pz = MFMA(wdh[0], b0p, bdC, 0, 0, 0);
        pz = MFMA(wdh[1], b1p, pz, 0, 0, 0);
        pz = MFMA(wdlo[0], b0p, pz, 0, 0, 0);
        pz = MFMA(wdlo[1], b1p, pz, 0, 0, 0);
        *(f32x4*)&out[(size_t)(brow + m) * (OUT_STEPS * Fdim) + (OUT_STEPS - 1) * Fdim + 16 * w + q * 4] = pz;
    }
}

extern "C" void kernel_launch(void* const* d_in, const int* in_sizes, int n_in,
                              void* d_out, int out_size, void* d_ws, size_t ws_size,
                              hipStream_t stream) {
    (void)in_sizes; (void)n_in; (void)out_size; (void)d_ws; (void)ws_size;
    const float* x  = (const float*)d_in[0];
    const float* W1 = (const float*)d_in[1];
    const float* U1 = (const float*)d_in[2];
    const float* b1 = (const float*)d_in[3];
    const float* W2 = (const float*)d_in[4];
    const float* U2 = (const float*)d_in[5];
    const float* b2 = (const float*)d_in[6];
    const float* Wd = (const float*)d_in[7];
    const float* bd = (const float*)d_in[8];
    float* out = (float*)d_out;

    lstm_v19<<<dim3(NBLK), dim3(NTHR), 0, stream>>>(
        x, W1, U1, b1, W2, U2, b2, Wd, bd, out);
}